// Round 8
// baseline (566.581 us; speedup 1.0000x reference)
//
#include <hip/hip_runtime.h>
#include <hip/hip_bf16.h>
#include <cstddef>

static constexpr int BATCH = 16;   // B

typedef __attribute__((ext_vector_type(8))) short bf16x8;
typedef __attribute__((ext_vector_type(4))) float f32x4;

__device__ __forceinline__ unsigned short f2bf(float f) {
  unsigned u = __float_as_uint(f);
  return (unsigned short)((u + 0x7fffu + ((u >> 16) & 1u)) >> 16);  // RNE
}

__global__ void init_kernel(float* __restrict__ tail, int n) {
  for (int i = threadIdx.x; i < n; i += 256) tail[i] = 0.f;
}

// ---- convert the 12 block-phase weight matrices to bf16 (layout [o][cin]) --
struct WcvtArgs { const float* p[12]; int sz[12]; int off[12]; };
__global__ __launch_bounds__(256)
void wcvt_kernel(WcvtArgs a, unsigned short* __restrict__ dst) {
  const int t = blockIdx.x;
  const float* src = a.p[t];
  unsigned short* d = dst + a.off[t];
  const int sz = a.sz[t];
  for (int i = blockIdx.y * 256 + threadIdx.x; i < sz; i += 16 * 256)
    d[i] = f2bf(src[i]);
}

// ---------------- q/k conv: f32 [b][c][n] -> bf16, dual layouts -------------
// TR=0: Yt[b][n][64c]  (Q operands).  TR=1: Yc[b][c][n]  (K operands).
template<int TR>
__global__ __launch_bounds__(256)
void conv_qk_kernel(const float* __restrict__ X, const float* __restrict__ W,
                    const float* __restrict__ bias, unsigned short* __restrict__ Y) {
  __shared__ float wsT[64][4];
  const int tid = threadIdx.x;
  const int o0 = blockIdx.x << 2;
  const int b  = blockIdx.z;
  const int px = (blockIdx.y << 9) + (tid << 1);
  {
    int c = tid >> 2, k = tid & 3;
    wsT[c][k] = W[((o0 + k) << 6) + c];
  }
  __syncthreads();
  float acc[4][2] = {};
  const float* xb = X + ((size_t)b << 16) + px;
#pragma unroll 4
  for (int c = 0; c < 64; ++c) {
    float2 xv = *reinterpret_cast<const float2*>(xb + (c << 10));
    float4 w = *reinterpret_cast<const float4*>(wsT[c]);
    acc[0][0] = fmaf(w.x, xv.x, acc[0][0]); acc[0][1] = fmaf(w.x, xv.y, acc[0][1]);
    acc[1][0] = fmaf(w.y, xv.x, acc[1][0]); acc[1][1] = fmaf(w.y, xv.y, acc[1][1]);
    acc[2][0] = fmaf(w.z, xv.x, acc[2][0]); acc[2][1] = fmaf(w.z, xv.y, acc[2][1]);
    acc[3][0] = fmaf(w.w, xv.x, acc[3][0]); acc[3][1] = fmaf(w.w, xv.y, acc[3][1]);
  }
  float b0 = bias[o0], b1 = bias[o0 + 1], b2 = bias[o0 + 2], b3 = bias[o0 + 3];
  if (TR == 0) {
    ushort4 v0, v1;
    v0.x = f2bf(acc[0][0] + b0); v0.y = f2bf(acc[1][0] + b1);
    v0.z = f2bf(acc[2][0] + b2); v0.w = f2bf(acc[3][0] + b3);
    v1.x = f2bf(acc[0][1] + b0); v1.y = f2bf(acc[1][1] + b1);
    v1.z = f2bf(acc[2][1] + b2); v1.w = f2bf(acc[3][1] + b3);
    unsigned short* yt = Y + ((size_t)b << 16) + ((size_t)px << 6) + o0;
    *reinterpret_cast<ushort4*>(yt) = v0;
    *reinterpret_cast<ushort4*>(yt + 64) = v1;
  } else {
    float bv[4] = {b0, b1, b2, b3};
#pragma unroll
    for (int k = 0; k < 4; ++k) {
      ushort2 v;
      v.x = f2bf(acc[k][0] + bv[k]); v.y = f2bf(acc[k][1] + bv[k]);
      *reinterpret_cast<ushort2*>(Y + ((size_t)b << 16) + ((size_t)(o0 + k) << 10) + px) = v;
    }
  }
}

// ---- MFMA fused PV: PART[jc][b,c,i] = sum_{j in chunk} exp(-E[i,j]) KB[c,j] -
__global__ __launch_bounds__(256)
void pv_mfma_kernel(const unsigned short* __restrict__ QAt,
                    const unsigned short* __restrict__ QBt,
                    const unsigned short* __restrict__ KBc,
                    float* __restrict__ PART, float* __restrict__ bsum) {
  __shared__ __align__(16) unsigned short Ai[4096];
  __shared__ __align__(16) unsigned short Bj[4096];
  __shared__ __align__(16) unsigned short Pl[4096];
  __shared__ float red[256];
  const int tid = threadIdx.x;
  const int lane = tid & 63, w = tid >> 6;
  const int g = lane >> 4, m = lane & 15;
  const int i0 = blockIdx.x << 6;
  const int jbase = blockIdx.y << 8;
  const int b = blockIdx.z;
  const size_t nb = (size_t)b << 16;

  {
    const unsigned short* src = QAt + nb + ((size_t)i0 << 6);
#pragma unroll
    for (int s = 0; s < 2; ++s) {
      int idx = tid + (s << 8);
      int n = idx >> 3, cc = idx & 7;
      bf16x8 v = *reinterpret_cast<const bf16x8*>(src + (n << 6) + ((cc ^ (n & 7)) << 3));
      *reinterpret_cast<bf16x8*>(Ai + (idx << 3)) = v;
    }
  }
  f32x4 accO[4];
#pragma unroll
  for (int n = 0; n < 4; ++n) accO[n] = (f32x4){0.f, 0.f, 0.f, 0.f};
  float psum = 0.f;

  for (int jt = 0; jt < 4; ++jt) {
    const int j0 = jbase + (jt << 6);
    __syncthreads();
    {
      const unsigned short* src = QBt + nb + ((size_t)j0 << 6);
#pragma unroll
      for (int s = 0; s < 2; ++s) {
        int idx = tid + (s << 8);
        int n = idx >> 3, cc = idx & 7;
        bf16x8 v = *reinterpret_cast<const bf16x8*>(src + (n << 6) + ((cc ^ (n & 7)) << 3));
        *reinterpret_cast<bf16x8*>(Bj + (idx << 3)) = v;
      }
    }
    __syncthreads();
    const int jrow = (w << 4) | m;
    bf16x8 a0 = *reinterpret_cast<const bf16x8*>(Bj + (jrow << 6) + ((g ^ (jrow & 7)) << 3));
    bf16x8 a1 = *reinterpret_cast<const bf16x8*>(Bj + (jrow << 6) + (((g + 4) ^ (jrow & 7)) << 3));
    f32x4 e[4];
#pragma unroll
    for (int n = 0; n < 4; ++n) {
      const int irow = (n << 4) | m;
      bf16x8 b0v = *reinterpret_cast<const bf16x8*>(Ai + (irow << 6) + ((g ^ (irow & 7)) << 3));
      bf16x8 b1v = *reinterpret_cast<const bf16x8*>(Ai + (irow << 6) + (((g + 4) ^ (irow & 7)) << 3));
      e[n] = (f32x4){0.f, 0.f, 0.f, 0.f};
      e[n] = __builtin_amdgcn_mfma_f32_16x16x32_bf16(a0, b0v, e[n], 0, 0, 0);
      e[n] = __builtin_amdgcn_mfma_f32_16x16x32_bf16(a1, b1v, e[n], 0, 0, 0);
    }
    const int j = (w << 4) | (g << 2);
#pragma unroll
    for (int n = 0; n < 4; ++n) {
      const int irow = (n << 4) | m;
      float p0 = __expf(-e[n][0]), p1 = __expf(-e[n][1]);
      float p2 = __expf(-e[n][2]), p3 = __expf(-e[n][3]);
      psum += (p0 + p1) + (p2 + p3);
      unsigned pk01 = (unsigned)f2bf(p0) | ((unsigned)f2bf(p1) << 16);
      unsigned pk23 = (unsigned)f2bf(p2) | ((unsigned)f2bf(p3) << 16);
      int base = irow << 6;
      int off0 = base + ((((j) >> 3) ^ (irow & 7)) << 3) + (j & 7);
      int off2 = base + ((((j + 2) >> 3) ^ (irow & 7)) << 3) + ((j + 2) & 7);
      *reinterpret_cast<unsigned*>(Pl + off0) = pk01;
      *reinterpret_cast<unsigned*>(Pl + off2) = pk23;
    }
    const int crow = (w << 4) | m;
    const unsigned short* kbp = KBc + nb + ((size_t)crow << 10) + j0 + (g << 3);
    bf16x8 ka0 = *reinterpret_cast<const bf16x8*>(kbp);
    bf16x8 ka1 = *reinterpret_cast<const bf16x8*>(kbp + 32);
    __syncthreads();
#pragma unroll
    for (int n = 0; n < 4; ++n) {
      const int irow = (n << 4) | m;
      bf16x8 p0 = *reinterpret_cast<const bf16x8*>(Pl + (irow << 6) + ((g ^ (irow & 7)) << 3));
      bf16x8 p1 = *reinterpret_cast<const bf16x8*>(Pl + (irow << 6) + (((g + 4) ^ (irow & 7)) << 3));
      accO[n] = __builtin_amdgcn_mfma_f32_16x16x32_bf16(ka0, p0, accO[n], 0, 0, 0);
      accO[n] = __builtin_amdgcn_mfma_f32_16x16x32_bf16(ka1, p1, accO[n], 0, 0, 0);
    }
  }
  float* OUT = PART + ((size_t)blockIdx.y << 20) + ((size_t)(b * 64) << 10);
#pragma unroll
  for (int n = 0; n < 4; ++n) {
    const int ig = i0 + (n << 4) + m;
    const int c = (w << 4) + (g << 2);
#pragma unroll
    for (int r = 0; r < 4; ++r)
      OUT[((size_t)(c + r) << 10) + ig] = accO[n][r];
  }
  red[tid] = psum; __syncthreads();
  for (int s = 128; s > 0; s >>= 1) {
    if (tid < s) red[tid] += red[tid + s];
    __syncthreads();
  }
  if (tid == 0) atomicAdd(bsum + b, red[0]);
}

// ---- MFMA fused PtV: PART[ic][b,c,j] = sum_{i in chunk} exp(-E[i,j]) KA[c,i]
__global__ __launch_bounds__(256)
void tpv_mfma_kernel(const unsigned short* __restrict__ QAt,
                     const unsigned short* __restrict__ QBt,
                     const unsigned short* __restrict__ KAc,
                     float* __restrict__ PART) {
  __shared__ __align__(16) unsigned short Bj[4096];
  __shared__ __align__(16) unsigned short Ai[4096];
  __shared__ __align__(16) unsigned short Pl[4096];
  const int tid = threadIdx.x;
  const int lane = tid & 63, w = tid >> 6;
  const int g = lane >> 4, m = lane & 15;
  const int j0 = blockIdx.x << 6;
  const int ibase = blockIdx.y << 8;
  const int b = blockIdx.z;
  const size_t nb = (size_t)b << 16;

  {
    const unsigned short* src = QBt + nb + ((size_t)j0 << 6);
#pragma unroll
    for (int s = 0; s < 2; ++s) {
      int idx = tid + (s << 8);
      int n = idx >> 3, cc = idx & 7;
      bf16x8 v = *reinterpret_cast<const bf16x8*>(src + (n << 6) + ((cc ^ (n & 7)) << 3));
      *reinterpret_cast<bf16x8*>(Bj + (idx << 3)) = v;
    }
  }
  f32x4 accO[4];
#pragma unroll
  for (int n = 0; n < 4; ++n) accO[n] = (f32x4){0.f, 0.f, 0.f, 0.f};

  for (int it = 0; it < 4; ++it) {
    const int i0 = ibase + (it << 6);
    __syncthreads();
    {
      const unsigned short* src = QAt + nb + ((size_t)i0 << 6);
#pragma unroll
      for (int s = 0; s < 2; ++s) {
        int idx = tid + (s << 8);
        int n = idx >> 3, cc = idx & 7;
        bf16x8 v = *reinterpret_cast<const bf16x8*>(src + (n << 6) + ((cc ^ (n & 7)) << 3));
        *reinterpret_cast<bf16x8*>(Ai + (idx << 3)) = v;
      }
    }
    __syncthreads();
    const int irow_a = (w << 4) | m;
    bf16x8 a0 = *reinterpret_cast<const bf16x8*>(Ai + (irow_a << 6) + ((g ^ (irow_a & 7)) << 3));
    bf16x8 a1 = *reinterpret_cast<const bf16x8*>(Ai + (irow_a << 6) + (((g + 4) ^ (irow_a & 7)) << 3));
    f32x4 e[4];
#pragma unroll
    for (int n = 0; n < 4; ++n) {
      const int jrow = (n << 4) | m;
      bf16x8 b0v = *reinterpret_cast<const bf16x8*>(Bj + (jrow << 6) + ((g ^ (jrow & 7)) << 3));
      bf16x8 b1v = *reinterpret_cast<const bf16x8*>(Bj + (jrow << 6) + (((g + 4) ^ (jrow & 7)) << 3));
      e[n] = (f32x4){0.f, 0.f, 0.f, 0.f};
      e[n] = __builtin_amdgcn_mfma_f32_16x16x32_bf16(a0, b0v, e[n], 0, 0, 0);
      e[n] = __builtin_amdgcn_mfma_f32_16x16x32_bf16(a1, b1v, e[n], 0, 0, 0);
    }
    const int i = (w << 4) | (g << 2);
#pragma unroll
    for (int n = 0; n < 4; ++n) {
      const int jrow = (n << 4) | m;
      float p0 = __expf(-e[n][0]), p1 = __expf(-e[n][1]);
      float p2 = __expf(-e[n][2]), p3 = __expf(-e[n][3]);
      unsigned pk01 = (unsigned)f2bf(p0) | ((unsigned)f2bf(p1) << 16);
      unsigned pk23 = (unsigned)f2bf(p2) | ((unsigned)f2bf(p3) << 16);
      int base = jrow << 6;
      int off0 = base + ((((i) >> 3) ^ (jrow & 7)) << 3) + (i & 7);
      int off2 = base + ((((i + 2) >> 3) ^ (jrow & 7)) << 3) + ((i + 2) & 7);
      *reinterpret_cast<unsigned*>(Pl + off0) = pk01;
      *reinterpret_cast<unsigned*>(Pl + off2) = pk23;
    }
    const int crow = (w << 4) | m;
    const unsigned short* kap = KAc + nb + ((size_t)crow << 10) + i0 + (g << 3);
    bf16x8 ka0 = *reinterpret_cast<const bf16x8*>(kap);
    bf16x8 ka1 = *reinterpret_cast<const bf16x8*>(kap + 32);
    __syncthreads();
#pragma unroll
    for (int n = 0; n < 4; ++n) {
      const int jrow = (n << 4) | m;
      bf16x8 p0 = *reinterpret_cast<const bf16x8*>(Pl + (jrow << 6) + ((g ^ (jrow & 7)) << 3));
      bf16x8 p1 = *reinterpret_cast<const bf16x8*>(Pl + (jrow << 6) + (((g + 4) ^ (jrow & 7)) << 3));
      accO[n] = __builtin_amdgcn_mfma_f32_16x16x32_bf16(ka0, p0, accO[n], 0, 0, 0);
      accO[n] = __builtin_amdgcn_mfma_f32_16x16x32_bf16(ka1, p1, accO[n], 0, 0, 0);
    }
  }
  float* OUT = PART + ((size_t)blockIdx.y << 20) + ((size_t)(b * 64) << 10);
#pragma unroll
  for (int n = 0; n < 4; ++n) {
    const int jg = j0 + (n << 4) + m;
    const int c = (w << 4) + (g << 2);
#pragma unroll
    for (int r = 0; r < 4; ++r)
      OUT[((size_t)(c + r) << 10) + jg] = accO[n][r];
  }
}

// ---- merge: Y0[b][n][0:64] = XR, [64:128] = (sum of 4 partials)/bsum, bf16 --
__global__ __launch_bounds__(256)
void merge_kernel(const float* __restrict__ PART, const float* __restrict__ XR,
                  const float* __restrict__ bsum, unsigned short* __restrict__ Y0) {
  __shared__ float ts[128][66];
  const int tid = threadIdx.x;
  const int n0 = blockIdx.x << 6;
  const int b = blockIdx.y;
  const float invS = 1.f / bsum[b];
  const size_t M1 = (size_t)1 << 20;
#pragma unroll
  for (int it = 0; it < 4; ++it) {
    int idx = it * 256 + tid;
    int c = idx >> 4, nq = (idx & 15) << 2;
    float4 v = *reinterpret_cast<const float4*>(XR + ((size_t)(b * 64 + c) << 10) + n0 + nq);
    ts[c][nq] = v.x; ts[c][nq + 1] = v.y; ts[c][nq + 2] = v.z; ts[c][nq + 3] = v.w;
  }
#pragma unroll
  for (int it = 0; it < 4; ++it) {
    int idx = it * 256 + tid;
    int c = idx >> 4, nq = (idx & 15) << 2;
    const float* p = PART + ((size_t)(b * 64 + c) << 10) + n0 + nq;
    float4 a = *reinterpret_cast<const float4*>(p);
    float4 b4 = *reinterpret_cast<const float4*>(p + M1);
    float4 c4 = *reinterpret_cast<const float4*>(p + 2 * M1);
    float4 d4 = *reinterpret_cast<const float4*>(p + 3 * M1);
    ts[64 + c][nq]     = ((a.x + b4.x) + (c4.x + d4.x)) * invS;
    ts[64 + c][nq + 1] = ((a.y + b4.y) + (c4.y + d4.y)) * invS;
    ts[64 + c][nq + 2] = ((a.z + b4.z) + (c4.z + d4.z)) * invS;
    ts[64 + c][nq + 3] = ((a.w + b4.w) + (c4.w + d4.w)) * invS;
  }
  __syncthreads();
  const int n = tid >> 2, c0 = (tid & 3) << 5;
  unsigned short* dst = Y0 + ((size_t)(b * 1024 + n0 + n) << 7) + c0;
#pragma unroll
  for (int q8 = 0; q8 < 4; ++q8) {
    const int cb = c0 + (q8 << 3);
    unsigned w0 = (unsigned)f2bf(ts[cb + 0][n]) | ((unsigned)f2bf(ts[cb + 1][n]) << 16);
    unsigned w1 = (unsigned)f2bf(ts[cb + 2][n]) | ((unsigned)f2bf(ts[cb + 3][n]) << 16);
    unsigned w2 = (unsigned)f2bf(ts[cb + 4][n]) | ((unsigned)f2bf(ts[cb + 5][n]) << 16);
    unsigned w3 = (unsigned)f2bf(ts[cb + 6][n]) | ((unsigned)f2bf(ts[cb + 7][n]) << 16);
    *reinterpret_cast<uint4*>(dst + (q8 << 3)) = make_uint4(w0, w1, w2, w3);
  }
}

// ---- MFMA conv: Y[b][n][o] = sum_c W[o][c] X[b][n][c]; all bf16, f32 acc ---
template<int CIN>
__global__ __launch_bounds__(256)
void conv_mfma_kernel(const unsigned short* __restrict__ Xin,
                      const unsigned short* __restrict__ Wb,
                      unsigned short* __restrict__ Yout,
                      float* __restrict__ outSums, int COUT) {
  const int tid = threadIdx.x;
  const int lane = tid & 63, w = tid >> 6;
  const int g = lane >> 4, m = lane & 15;
  const int o0 = (blockIdx.x << 6) + (w << 4);
  const int n0 = blockIdx.y << 6;
  const int b = blockIdx.z;
  const unsigned short* Xb = Xin + (size_t)(b * 1024 + n0) * CIN + (g << 3);
  const unsigned short* Wr = Wb + (size_t)(o0 + m) * CIN + (g << 3);
  f32x4 acc[4];
#pragma unroll
  for (int nt = 0; nt < 4; ++nt) acc[nt] = (f32x4){0.f, 0.f, 0.f, 0.f};
#pragma unroll
  for (int k0 = 0; k0 < CIN; k0 += 32) {
    bf16x8 af = *reinterpret_cast<const bf16x8*>(Wr + k0);
#pragma unroll
    for (int nt = 0; nt < 4; ++nt) {
      bf16x8 bv = *reinterpret_cast<const bf16x8*>(Xb + (size_t)((nt << 4) + m) * CIN + k0);
      acc[nt] = __builtin_amdgcn_mfma_f32_16x16x32_bf16(af, bv, acc[nt], 0, 0, 0);
    }
  }
  unsigned short* Yb = Yout + (size_t)(b * 1024 + n0) * COUT + o0 + (g << 2);
#pragma unroll
  for (int nt = 0; nt < 4; ++nt) {
    ushort4 v;
    v.x = f2bf(acc[nt][0]); v.y = f2bf(acc[nt][1]);
    v.z = f2bf(acc[nt][2]); v.w = f2bf(acc[nt][3]);
    *reinterpret_cast<ushort4*>(Yb + (size_t)((nt << 4) + m) * COUT) = v;
  }
  if (outSums) {
    float s[4], q[4];
#pragma unroll
    for (int r = 0; r < 4; ++r) {
      s[r] = acc[0][r] + acc[1][r] + acc[2][r] + acc[3][r];
      q[r] = acc[0][r] * acc[0][r] + acc[1][r] * acc[1][r]
           + acc[2][r] * acc[2][r] + acc[3][r] * acc[3][r];
    }
#pragma unroll
    for (int r = 0; r < 4; ++r) {
      for (int off = 1; off < 16; off <<= 1) {
        s[r] += __shfl_xor(s[r], off);
        q[r] += __shfl_xor(q[r], off);
      }
    }
    if (m == 0) {
#pragma unroll
      for (int r = 0; r < 4; ++r) {
        atomicAdd(&outSums[o0 + (g << 2) + r], s[r]);
        atomicAdd(&outSums[256 + o0 + (g << 2) + r], q[r]);
      }
    }
  }
}

// ---- finish: MODE 0: relu(bn0(T)); 1: relu(bn0(T)+S); 2: relu(bn0(T)+bn1(S))
template<int C, int MODE>
__global__ __launch_bounds__(256)
void finish_kernel(const unsigned short* __restrict__ T,
                   const float* __restrict__ sums0, const float* __restrict__ g0f,
                   const float* __restrict__ b0f,
                   const unsigned short* __restrict__ S,
                   const float* __restrict__ sums1, const float* __restrict__ g1f,
                   const float* __restrict__ b1f,
                   unsigned short* __restrict__ OUT) {
  __shared__ float sc0[C], sh0[C];
  __shared__ float sc1[(MODE == 2) ? C : 1], sh1[(MODE == 2) ? C : 1];
  const int tid = threadIdx.x;
  const float invN = 1.f / 16384.f;
  for (int c = tid; c < C; c += 256) {
    float mm = sums0[c] * invN;
    float vv = sums0[256 + c] * invN - mm * mm;
    float s = g0f[c] * rsqrtf(vv + 1e-5f);
    sc0[c] = s; sh0[c] = b0f[c] - mm * s;
    if (MODE == 2) {
      float m1 = sums1[c] * invN;
      float v1 = sums1[256 + c] * invN - m1 * m1;
      float s1 = g1f[c] * rsqrtf(v1 + 1e-5f);
      sc1[c] = s1; sh1[c] = b1f[c] - m1 * s1;
    }
  }
  __syncthreads();
  const size_t i8 = ((size_t)blockIdx.x * 256 + tid) << 3;
  const int c0 = (int)(i8 & (size_t)(C - 1));
  uint4 tv = *reinterpret_cast<const uint4*>(T + i8);
  uint4 sv = make_uint4(0, 0, 0, 0);
  if (MODE != 0) sv = *reinterpret_cast<const uint4*>(S + i8);
  unsigned tw[4] = {tv.x, tv.y, tv.z, tv.w};
  unsigned sw[4] = {sv.x, sv.y, sv.z, sv.w};
  unsigned ow[4];
#pragma unroll
  for (int jw = 0; jw < 4; ++jw) {
    unsigned r = 0;
#pragma unroll
    for (int h = 0; h < 2; ++h) {
      int c = c0 + jw * 2 + h;
      float x = __uint_as_float(((tw[jw] >> (h * 16)) & 0xffffu) << 16);
      x = fmaf(x, sc0[c], sh0[c]);
      if (MODE == 1) x += __uint_as_float(((sw[jw] >> (h * 16)) & 0xffffu) << 16);
      if (MODE == 2) {
        float y = __uint_as_float(((sw[jw] >> (h * 16)) & 0xffffu) << 16);
        x += fmaf(y, sc1[c], sh1[c]);
      }
      x = fmaxf(x, 0.f);
      r |= ((unsigned)f2bf(x)) << (h * 16);
    }
    ow[jw] = r;
  }
  *reinterpret_cast<uint4*>(OUT + i8) = make_uint4(ow[0], ow[1], ow[2], ow[3]);
}

// ---- writeout: out[b][c][n] f32 = bn(F[b][n][c]) via LDS transpose ---------
__global__ __launch_bounds__(256)
void writeout_t_kernel(const unsigned short* __restrict__ F, const float* __restrict__ sums,
                       const float* __restrict__ gam, const float* __restrict__ bet,
                       float* __restrict__ out) {
  __shared__ float ts[64][66];
  __shared__ float sc[64], sh[64];
  const int tid = threadIdx.x;
  const float invN = 1.f / 16384.f;
  if (tid < 64) {
    float mm = sums[tid] * invN;
    float vv = sums[256 + tid] * invN - mm * mm;
    float s = gam[tid] * rsqrtf(vv + 1e-5f);
    sc[tid] = s; sh[tid] = bet[tid] - mm * s;
  }
  __syncthreads();
  const int n0 = blockIdx.x << 6;
  const int b = blockIdx.y;
  {
    const int n = tid >> 2, c0 = (tid & 3) << 4;
    const unsigned short* Fr = F + ((size_t)(b * 1024 + n0 + n) << 6) + c0;
    uint4 v0 = *reinterpret_cast<const uint4*>(Fr);
    uint4 v1 = *reinterpret_cast<const uint4*>(Fr + 8);
    unsigned vw[8] = {v0.x, v0.y, v0.z, v0.w, v1.x, v1.y, v1.z, v1.w};
#pragma unroll
    for (int jw = 0; jw < 8; ++jw) {
      int c = c0 + jw * 2;
      float x0 = __uint_as_float((vw[jw] & 0xffffu) << 16);
      float x1 = __uint_as_float((vw[jw] >> 16) << 16);
      ts[c][n] = fmaf(x0, sc[c], sh[c]);
      ts[c + 1][n] = fmaf(x1, sc[c + 1], sh[c + 1]);
    }
  }
  __syncthreads();
  const int c = tid >> 2, nq = (tid & 3) << 4;
  float* orow = out + ((size_t)(b * 64 + c) << 10) + n0 + nq;
#pragma unroll
  for (int q = 0; q < 4; ++q) {
    float4 ov;
    ov.x = ts[c][nq + q * 4 + 0]; ov.y = ts[c][nq + q * 4 + 1];
    ov.z = ts[c][nq + q * 4 + 2]; ov.w = ts[c][nq + q * 4 + 3];
    *reinterpret_cast<float4*>(orow + q * 4) = ov;
  }
}

// ============================ host side =====================================
extern "C" void kernel_launch(void* const* d_in, const int* in_sizes, int n_in,
                              void* d_out, int out_size, void* d_ws, size_t ws_size,
                              hipStream_t stream) {
  float* wsf = (float*)d_ws;
  const size_t M1 = (size_t)1 << 20;
  const size_t H1 = (size_t)1 << 19;

  // ---- workspace layout (floats), NON-OVERLAPPING (r7 bug: 128/256-ch bf16
  // tensors are 1M/2M floats, not 0.5M) ----
  unsigned short* QAt = (unsigned short*)wsf;                 // [0, 0.5M)
  unsigned short* QBt = (unsigned short*)(wsf + H1);          // [0.5M, 1M)
  unsigned short* KAc = (unsigned short*)(wsf + 2 * H1);      // [1M, 1.5M)
  unsigned short* KBc = (unsigned short*)(wsf + 3 * H1);      // [1.5M, 2M)
  float* PART = wsf + 2 * M1;                                 // [2M, 6M)
  unsigned short* Y0A = (unsigned short*)(wsf + 6 * M1);      // [6M, 7M)
  unsigned short* Y0B = (unsigned short*)(wsf + 7 * M1);      // [7M, 8M)
  unsigned short* T1  = (unsigned short*)(wsf + 8 * M1);      // [8M, 9M)
  unsigned short* T2  = (unsigned short*)(wsf + 9 * M1);      // [9M, 10M)
  unsigned short* O1  = (unsigned short*)(wsf + 10 * M1);     // [10M, 11M)
  unsigned short* T3  = (unsigned short*)(wsf + 11 * M1);     // [11M, 13M) 256ch
  unsigned short* T4  = (unsigned short*)(wsf + 13 * M1);     // [13M, 15M)
  unsigned short* T5  = (unsigned short*)(wsf + 15 * M1);     // [15M, 17M)
  unsigned short* Fb  = (unsigned short*)(wsf + 17 * M1);     // [17M, 17.5M)
  float* tail = wsf + 17 * M1 + H1;
  float* bsum = tail;
  float* stats = tail + 16;                                   // 12 * 512
  unsigned short* wbf = (unsigned short*)(tail + 16 + 12 * 512);

  const float* pp[46];
  for (int i = 0; i < 46 && i < n_in; ++i) pp[i] = (const float*)d_in[i];
  const float* XAF = pp[0];
  const float* XBF = pp[1];

  init_kernel<<<1, 256, 0, stream>>>(tail, 16 + 12 * 512);

  // ---- convert block-phase weights to bf16 ----
  const int widx[12] = {10, 13, 16, 19, 22, 25, 28, 31, 34, 37, 40, 43};
  WcvtArgs wa;
  int woff[12];
  {
    int run = 0;
    for (int i = 0; i < 12; ++i) {
      wa.p[i] = pp[widx[i]];
      wa.sz[i] = in_sizes[widx[i]];
      wa.off[i] = run; woff[i] = run;
      run += in_sizes[widx[i]];
    }
  }
  wcvt_kernel<<<dim3(12, 16), 256, 0, stream>>>(wa, wbf);

  float* ST[12];
  for (int i = 0; i < 12; ++i) ST[i] = stats + i * 512;

  // ---- q/k convs -> bf16 dual layouts ----
  dim3 gq(16, 2, BATCH);
  conv_qk_kernel<0><<<gq, 256, 0, stream>>>(XAF, pp[2], pp[3], QAt);
  conv_qk_kernel<0><<<gq, 256, 0, stream>>>(XBF, pp[4], pp[5], QBt);
  conv_qk_kernel<1><<<gq, 256, 0, stream>>>(XAF, pp[6], pp[7], KAc);
  conv_qk_kernel<1><<<gq, 256, 0, stream>>>(XBF, pp[8], pp[9], KBc);

  // ---- MFMA attention + merge-to-concat ----
  pv_mfma_kernel<<<dim3(16, 4, BATCH), 256, 0, stream>>>(QAt, QBt, KBc, PART, bsum);
  merge_kernel<<<dim3(16, BATCH), 256, 0, stream>>>(PART, XAF, bsum, Y0A);
  tpv_mfma_kernel<<<dim3(16, 4, BATCH), 256, 0, stream>>>(QAt, QBt, KAc, PART);
  merge_kernel<<<dim3(16, BATCH), 256, 0, stream>>>(PART, XBF, bsum, Y0B);

  for (int sbi = 0; sbi < 2; ++sbi) {
    const unsigned short* Y0 = sbi ? Y0B : Y0A;
    const int base1 = sbi ? 16 : 10;
    const int base2 = sbi ? 31 : 22;
    const int baseo = sbi ? 43 : 40;
    const unsigned short* w11 = wbf + woff[sbi ? 2 : 0];
    const unsigned short* w12 = wbf + woff[sbi ? 3 : 1];
    const unsigned short* w21 = wbf + woff[sbi ? 7 : 4];
    const unsigned short* w22 = wbf + woff[sbi ? 8 : 5];
    const unsigned short* w2s = wbf + woff[sbi ? 9 : 6];
    const unsigned short* wo  = wbf + woff[sbi ? 11 : 10];
    float* s1 = ST[sbi * 6 + 0];
    float* s2 = ST[sbi * 6 + 1];
    float* s3 = ST[sbi * 6 + 2];
    float* s4 = ST[sbi * 6 + 3];
    float* s5 = ST[sbi * 6 + 4];
    float* s6 = ST[sbi * 6 + 5];

    // block 1 (128 -> 128)
    conv_mfma_kernel<128><<<dim3(2, 16, BATCH), 256, 0, stream>>>(Y0, w11, T1, s1, 128);
    finish_kernel<128, 0><<<1024, 256, 0, stream>>>(
        T1, s1, pp[base1 + 1], pp[base1 + 2], nullptr, nullptr, nullptr, nullptr, T1);
    conv_mfma_kernel<128><<<dim3(2, 16, BATCH), 256, 0, stream>>>(T1, w12, T2, s2, 128);
    finish_kernel<128, 1><<<1024, 256, 0, stream>>>(
        T2, s2, pp[base1 + 4], pp[base1 + 5], Y0, nullptr, nullptr, nullptr, O1);

    // block 2 (128 -> 256, with shortcut)
    conv_mfma_kernel<128><<<dim3(4, 16, BATCH), 256, 0, stream>>>(O1, w21, T3, s3, 256);
    finish_kernel<256, 0><<<2048, 256, 0, stream>>>(
        T3, s3, pp[base2 + 1], pp[base2 + 2], nullptr, nullptr, nullptr, nullptr, T3);
    conv_mfma_kernel<256><<<dim3(4, 16, BATCH), 256, 0, stream>>>(T3, w22, T4, s4, 256);
    conv_mfma_kernel<128><<<dim3(4, 16, BATCH), 256, 0, stream>>>(O1, w2s, T5, s5, 256);
    finish_kernel<256, 2><<<2048, 256, 0, stream>>>(
        T4, s4, pp[base2 + 4], pp[base2 + 5], T5, s5, pp[base2 + 7], pp[base2 + 8], T3);

    // output conv (256 -> 64) + BN + transpose out
    conv_mfma_kernel<256><<<dim3(1, 16, BATCH), 256, 0, stream>>>(T3, wo, Fb, s6, 64);
    writeout_t_kernel<<<dim3(16, BATCH), 256, 0, stream>>>(
        Fb, s6, pp[baseo + 1], pp[baseo + 2], (float*)d_out + sbi * M1);
  }
}